// Round 1
// baseline (771.392 us; speedup 1.0000x reference)
//
#include <hip/hip_runtime.h>

typedef __bf16 bf16;
typedef __bf16 bf16x8 __attribute__((ext_vector_type(8)));
typedef __bf16 bf16x4 __attribute__((ext_vector_type(4)));
typedef _Float16 f16;
typedef _Float16 f16x2 __attribute__((ext_vector_type(2)));
typedef _Float16 f16x4 __attribute__((ext_vector_type(4)));
typedef _Float16 f16x8 __attribute__((ext_vector_type(8)));
typedef float f32x4 __attribute__((ext_vector_type(4)));

__device__ __forceinline__ f32x4 mfma_qk(bf16x8 a, bf16x8 b, f32x4 c) {
    return __builtin_amdgcn_mfma_f32_16x16x32_bf16(a, b, c, 0, 0, 0);
}
// full-rate K=32 f16 MFMA for PV (legacy 16x16x16 runs at half rate)
__device__ __forceinline__ f32x4 mfma_pv32(f16x8 a, f16x8 b, f32x4 c) {
    return __builtin_amdgcn_mfma_f32_16x16x32_f16(a, b, c, 0, 0, 0);
}

// async global -> LDS, 16 bytes per lane (dest = wave-uniform base + lane*16)
#define GLOAD_LDS16(gp, lp)                                                    \
    __builtin_amdgcn_global_load_lds(                                          \
        (const __attribute__((address_space(1))) unsigned int*)(gp),           \
        (__attribute__((address_space(3))) unsigned int*)(lp), 16, 0, 0)

// ---------------------------------------------------------------------------
// Cast fp32 -> bf16: 4 weights (1024^2 each), key_value (8M), query (8M).
// ---------------------------------------------------------------------------
__global__ __launch_bounds__(256) void cast_inputs(
    const float* __restrict__ w0, const float* __restrict__ w1,
    const float* __restrict__ w2, const float* __restrict__ w3,
    const float* __restrict__ kv, const float* __restrict__ q,
    bf16* __restrict__ Wb, bf16* __restrict__ KVa, bf16* __restrict__ Qb) {
    long i4 = (long)blockIdx.x * 256 + threadIdx.x;  // float4 index
    const float* src;
    bf16* dst;
    long loc;
    if (i4 < 1048576) {            // 4 weights x 262144 float4
        int which = (int)(i4 >> 18);
        loc = (i4 & 262143) << 2;
        src = which == 0 ? w0 : which == 1 ? w1 : which == 2 ? w2 : w3;
        dst = Wb + ((long)which << 20);
    } else if (i4 < 3145728) {     // key_value
        loc = (i4 - 1048576) << 2;
        src = kv; dst = KVa;
    } else {                       // query
        loc = (i4 - 3145728) << 2;
        src = q; dst = Qb;
    }
    float4 f = *(const float4*)(src + loc);
    bf16x4 o;
    o[0] = (bf16)f.x; o[1] = (bf16)f.y; o[2] = (bf16)f.z; o[3] = (bf16)f.w;
    *(bf16x4*)(dst + loc) = o;
}

// ---------------------------------------------------------------------------
// Core GEMM: C[M,N] = A[M,K] @ W[N,K]^T + bias. M=8192, N=K=1024.
// 128x128 tile, BK=64, 4 waves each 64x64. Async global->LDS staging into
// XOR-swizzled pad-free layout: slot(row, c8) = row*8 + (c8 ^ (row&7));
// fragment b128 reads then spread over 8 bank-groups (conflict-free).
// om: 0 = bf16 row-major, 1 = f32 row-major, 2 = f16 V^T [b,h,d,skv].
// ---------------------------------------------------------------------------
__device__ __forceinline__ void gemm_core(
    const bf16* __restrict__ A, const bf16* __restrict__ Wt,
    const float* __restrict__ bias, void* __restrict__ Yv,
    const int om, bf16* smem, const int n0, const int m0) {
    constexpr int Kd = 1024, Nd = 1024;
    constexpr int TP = 132;  // om2 transpose row stride
    bf16* As = smem;          // 8192 halves (128 x 64, swizzled)
    bf16* Bs = smem + 8192;
    const int tid = threadIdx.x;
    const int wid = tid >> 6, lane = tid & 63;
    const int l16 = lane & 15, quad = lane >> 4;
    const int mh = (wid >> 1) * 64, nh = (wid & 1) * 64;

    f32x4 acc[4][4];
#pragma unroll
    for (int i = 0; i < 4; ++i)
#pragma unroll
        for (int j = 0; j < 4; ++j) acc[i][j] = (f32x4){0.f, 0.f, 0.f, 0.f};

    for (int k0 = 0; k0 < Kd; k0 += 64) {
#pragma unroll
        for (int j = 0; j < 4; ++j) {
            const int s = j * 256 + tid;
            const int r = s >> 3, c8 = (s & 7) ^ (r & 7);
            GLOAD_LDS16(A + (long)(m0 + r) * Kd + k0 + c8 * 8, &As[s * 8]);
            GLOAD_LDS16(Wt + (long)(n0 + r) * Kd + k0 + c8 * 8, &Bs[s * 8]);
        }
        __syncthreads();
#pragma unroll
        for (int kc = 0; kc < 2; ++kc) {
            bf16x8 af[4], bq[4];
#pragma unroll
            for (int i = 0; i < 4; ++i) {
                const int row = mh + i * 16 + l16;
                af[i] = *(const bf16x8*)&As[(row * 8 + ((kc * 4 + quad) ^ (row & 7))) * 8];
            }
#pragma unroll
            for (int i = 0; i < 4; ++i) {
                const int row = nh + i * 16 + l16;
                bq[i] = *(const bf16x8*)&Bs[(row * 8 + ((kc * 4 + quad) ^ (row & 7))) * 8];
            }
#pragma unroll
            for (int i = 0; i < 4; ++i)
#pragma unroll
                for (int j = 0; j < 4; ++j)
                    acc[i][j] = mfma_qk(af[i], bq[j], acc[i][j]);
        }
        __syncthreads();
    }

    if (om == 2) {
        // transpose tile through LDS as f16, then coalesced 16B stores
#pragma unroll
        for (int j = 0; j < 4; ++j) {
            const int col = nh + j * 16 + l16;
            const float bv = bias[n0 + col];
#pragma unroll
            for (int i = 0; i < 4; ++i)
#pragma unroll
                for (int p = 0; p < 2; ++p) {
                    f16x2 pk2;
                    pk2[0] = (f16)(acc[i][j][p * 2 + 0] + bv);
                    pk2[1] = (f16)(acc[i][j][p * 2 + 1] + bv);
                    *(f16x2*)&smem[col * TP + mh + i * 16 + quad * 4 + p * 2] = pk2;
                }
        }
        __syncthreads();
        // Vt[((b*16+h)*64+d)*2048 + skv]
        const int b_ = m0 >> 11, skv0 = m0 & 2047;
        const int rowc = tid & 15;
#pragma unroll
        for (int c = 0; c < 8; ++c) {
            const int col = (tid >> 4) + c * 16;
            const int colg = n0 + col;
            bf16x8 v = *(const bf16x8*)&smem[col * TP + rowc * 8];
            const long base = ((long)((b_ * 16 + (colg >> 6)) * 64 + (colg & 63))) << 11;
            *(bf16x8*)((bf16*)Yv + base + skv0 + rowc * 8) = v;
        }
    } else {
#pragma unroll
        for (int j = 0; j < 4; ++j) {
            const int col = n0 + nh + j * 16 + l16;
            const float bv = bias[col];
#pragma unroll
            for (int i = 0; i < 4; ++i)
#pragma unroll
                for (int r = 0; r < 4; ++r) {
                    int row = m0 + mh + i * 16 + quad * 4 + r;
                    float v = acc[i][j][r] + bv;
                    if (om == 1)
                        ((float*)Yv)[(long)row * Nd + col] = v;
                    else
                        ((bf16*)Yv)[(long)row * Nd + col] = (bf16)v;
                }
        }
    }
}

// Fused Q/K/V projections: one 1536-block launch (4 blocks/CU for the whole
// phase; the three GEMMs' barrier stalls hide each other). Chunked bijective
// XCD swizzle: each XCD gets 192 consecutive (z,y,x)-linear ids -> A-panel and
// W reuse stays within one XCD's L2.
__global__ __launch_bounds__(256) void proj_qkv(
    const bf16* __restrict__ Qb, const bf16* __restrict__ KVa,
    const bf16* __restrict__ Wb,
    const float* __restrict__ bq, const float* __restrict__ bk,
    const float* __restrict__ bv,
    bf16* __restrict__ Qw, bf16* __restrict__ Kw, f16* __restrict__ Vt) {
    __shared__ __align__(16) bf16 smem[16896];
    const int lin = blockIdx.x + (blockIdx.y << 3) + (blockIdx.z << 9);  // 0..1535
    const int nid = (lin & 7) * 192 + (lin >> 3);
    const int z = nid >> 9, rem = nid & 511;
    const int n0 = (rem & 7) << 7, m0 = (rem >> 3) << 7;
    if (z == 0)
        gemm_core(Qb, Wb, bq, Qw, 0, smem, n0, m0);
    else if (z == 1)
        gemm_core(KVa, Wb + (1l << 20), bk, Kw, 0, smem, n0, m0);
    else
        gemm_core(KVa, Wb + (2l << 20), bv, Vt, 2, smem, n0, m0);
}

__global__ __launch_bounds__(256) void gemm_o(
    const bf16* __restrict__ Cw, const bf16* __restrict__ Wo,
    const float* __restrict__ bo, float* __restrict__ out) {
    __shared__ __align__(16) bf16 smem[16896];
    const int lin = blockIdx.x + (blockIdx.y << 3);  // 0..511
    const int nid = (lin & 7) * 64 + (lin >> 3);
    gemm_core(Cw, Wo, bo, out, 1, smem, (nid & 7) << 7, (nid >> 3) << 7);
}

// ---------------------------------------------------------------------------
// StableMax cross-attention, transposed-score formulation.
// PV upgraded to full-rate 16x16x32 f16 MFMA: the k-permutation inside the
// 32-chunk is chosen as  k-slot 8q+4s+r  <->  kv 16s+4q+r, which makes the
// two 16-row QK outputs land exactly in each lane's B-fragment slots (no
// cross-lane shuffles); V^T is fetched as two f16x4 chunks per MFMA.
// XCD-swizzled block ids keep each (b,h)'s 512KB K/V panel in one L2.
// ---------------------------------------------------------------------------
__global__ __launch_bounds__(256, 4) void attn_kernel(
    const bf16* __restrict__ Q, const bf16* __restrict__ K,
    const f16* __restrict__ Vt, bf16* __restrict__ C) {
    constexpr int E = 1024, S = 2048;
    __shared__ __align__(16) char smem_raw[32768];
    bf16* Ks = (bf16*)smem_raw;             // [128 kv][64 d], swizzled chunks
    f16* VTs = (f16*)(smem_raw + 16384);    // [64 d][128 kv], swizzled chunks

    const int tid = threadIdx.x;
    const int wid = tid >> 6, lane = tid & 63;
    const int l16 = lane & 15, quad = lane >> 4;
    // chunked bijective XCD swizzle: 1024 blocks, 128 per XCD = 8 (b,h)
    // panels = 4MB K+V, exactly one XCD L2.
    const int lin = blockIdx.x + (blockIdx.y << 4) + (blockIdx.z << 8);
    const int nid = (lin & 7) * 128 + (lin >> 3);
    const int qt = nid & 15, h = (nid >> 4) & 15, b = nid >> 8;

    const long q0 = (long)b * S + qt * 128;
    const bf16* Qg = Q + q0 * E + h * 64;
    const bf16* Kg = K + (long)b * S * E + h * 64;
    const f16* Vg = Vt + ((long)(b * 16 + h) << 17);  // [d][2048]

    // Q B-fragments: B[k=d=quad*8+j][n=q=l16]
    bf16x8 qf[2][2];
#pragma unroll
    for (int mt = 0; mt < 2; ++mt)
#pragma unroll
        for (int kc = 0; kc < 2; ++kc)
            qf[mt][kc] = *(const bf16x8*)(Qg + (long)(wid * 32 + mt * 16 + l16) * E + kc * 32 + quad * 8);

    f32x4 ctx[2][4];   // ctx^T: lane holds d=dt*16+quad*4+r, q=l16
    float den[2] = {0.f, 0.f};
#pragma unroll
    for (int mt = 0; mt < 2; ++mt)
#pragma unroll
        for (int dt = 0; dt < 4; ++dt) ctx[mt][dt] = (f32x4){0.f, 0.f, 0.f, 0.f};

    for (int kv0 = 0; kv0 < S; kv0 += 128) {
        // stage K [128 kv][64 d]: swizzle slot = r*8 + (c8 ^ (r&7))
#pragma unroll
        for (int j = 0; j < 4; ++j) {
            const int s = j * 256 + tid;
            const int r = s >> 3, c8 = (s & 7) ^ (r & 7);
            GLOAD_LDS16(Kg + (long)(kv0 + r) * E + c8 * 8, &Ks[s * 8]);
        }
        // stage V^T [64 d][128 kv]: slot = r*16 + (c16 ^ (r&15))
#pragma unroll
        for (int j = 0; j < 4; ++j) {
            const int s = j * 256 + tid;
            const int r = s >> 4, c16 = (s & 15) ^ (r & 15);
            GLOAD_LDS16(Vg + (long)r * S + kv0 + c16 * 8, &VTs[s * 8]);
        }
        __syncthreads();

#pragma unroll
        for (int kvp = 0; kvp < 4; ++kvp) {
            // QK^T for the two 16-kv slices of this 32-chunk
            f32x4 sacc[2][2];  // [s][mt]
#pragma unroll
            for (int s = 0; s < 2; ++s) {
                const int rk = kvp * 32 + s * 16 + l16, rb = rk & 7;
                bf16x8 kf0 = *(const bf16x8*)&Ks[(rk * 8 + (quad ^ rb)) * 8];
                bf16x8 kf1 = *(const bf16x8*)&Ks[(rk * 8 + ((quad + 4) ^ rb)) * 8];
                __builtin_amdgcn_s_setprio(1);
#pragma unroll
                for (int mt = 0; mt < 2; ++mt) {
                    f32x4 t = mfma_qk(kf0, qf[mt][0], (f32x4){0.f, 0.f, 0.f, 0.f});
                    sacc[s][mt] = mfma_qk(kf1, qf[mt][1], t);
                }
                __builtin_amdgcn_s_setprio(0);
            }
            // stablemax: u = 1 + |x|/8 ; s = x>=0 ? u : 1/u; pack P as f16x8
            // B-fragment slot j = s*4+r at lane quad holds kv=16s+4*quad+r.
            f16x8 pp[2];
#pragma unroll
            for (int mt = 0; mt < 2; ++mt) {
#pragma unroll
                for (int s = 0; s < 2; ++s) {
                    float sv[4];
#pragma unroll
                    for (int r = 0; r < 4; ++r) {
                        float x = sacc[s][mt][r];
                        float u = __builtin_fmaf(__builtin_fabsf(x), 0.125f, 1.0f);
                        sv[r] = (x >= 0.f) ? u : __builtin_amdgcn_rcpf(u);
                        pp[mt][s * 4 + r] = (f16)sv[r];
                    }
                    den[mt] += (sv[0] + sv[1]) + (sv[2] + sv[3]);
                }
            }
            // PV: ctx^T += V^T-frag x P^T-frag (16x16x32 f16, full rate)
            // A-lane quad needs kv in {4q..4q+3} u {16+4q..16+4q+3}:
            // chunks c16l and c16l+2, half ho.
            const int c16l = 4 * kvp + (quad >> 1), ho = (quad & 1) * 4;
#pragma unroll
            for (int dt = 0; dt < 4; ++dt) {
                const int rv = dt * 16 + l16;
                f16x4 vlo = *(const f16x4*)&VTs[(rv * 16 + (c16l ^ l16)) * 8 + ho];
                f16x4 vhi = *(const f16x4*)&VTs[(rv * 16 + ((c16l + 2) ^ l16)) * 8 + ho];
                f16x8 vf = __builtin_shufflevector(vlo, vhi, 0, 1, 2, 3, 4, 5, 6, 7);
                __builtin_amdgcn_s_setprio(1);
#pragma unroll
                for (int mt = 0; mt < 2; ++mt)
                    ctx[mt][dt] = mfma_pv32(vf, pp[mt], ctx[mt][dt]);
                __builtin_amdgcn_s_setprio(0);
            }
        }
        __syncthreads();
    }

    // den: reduce across the 4 quads of each q column
    float scl[2];
#pragma unroll
    for (int mt = 0; mt < 2; ++mt) {
        float d = den[mt];
        d += __shfl_xor(d, 16);
        d += __shfl_xor(d, 32);
        scl[mt] = __builtin_amdgcn_rcpf(d);
    }

    // epilogue: ctx^T -> LDS transpose (overlay, stride 68) -> coalesced store
    bf16* Os = (bf16*)smem_raw;
#pragma unroll
    for (int mt = 0; mt < 2; ++mt)
#pragma unroll
        for (int dt = 0; dt < 4; ++dt) {
            bf16x4 o;
#pragma unroll
            for (int r = 0; r < 4; ++r) o[r] = (bf16)(ctx[mt][dt][r] * scl[mt]);
            *(bf16x4*)&Os[(wid * 32 + mt * 16 + l16) * 68 + dt * 16 + quad * 4] = o;
        }
    __syncthreads();
    {
        const int r = tid >> 1, c = (tid & 1) * 32;
        bf16* cp = C + (q0 + r) * E + h * 64 + c;
#pragma unroll
        for (int j = 0; j < 4; ++j)
            *(bf16x8*)(cp + j * 8) = *(const bf16x8*)&Os[r * 68 + c + j * 8];
    }
}

// ---------------------------------------------------------------------------
extern "C" void kernel_launch(void* const* d_in, const int* in_sizes, int n_in,
                              void* d_out, int out_size, void* d_ws, size_t ws_size,
                              hipStream_t stream) {
    const float* query = (const float*)d_in[0];
    const float* keyv  = (const float*)d_in[1];
    const float* Wq = (const float*)d_in[2];
    const float* bq = (const float*)d_in[3];
    const float* Wk = (const float*)d_in[4];
    const float* bk = (const float*)d_in[5];
    const float* Wv = (const float*)d_in[6];
    const float* bv = (const float*)d_in[7];
    const float* Wo = (const float*)d_in[8];
    const float* bo = (const float*)d_in[9];

    char* ws = (char*)d_ws;
    bf16* Wb  = (bf16*)ws;                  // 8 MB: Wq,Wk,Wv,Wo bf16
    bf16* KVa = (bf16*)(ws + (8l << 20));   // 16 MB kv bf16 (later Cw)
    bf16* Qb  = (bf16*)(ws + (24l << 20));  // 16 MB query bf16
    bf16* Qw  = (bf16*)(ws + (40l << 20));  // 16 MB
    f16*  Vt  = (f16*)(ws + (56l << 20));   // 16 MB V^T f16 [b,h,d,skv]
    bf16* Kw  = (bf16*)d_out;               // d_out dead until gemm_o: use as Kw
    bf16* Cw  = KVa;                        // alias: KVa dead after proj_qkv

    cast_inputs<<<20480, 256, 0, stream>>>(Wq, Wk, Wv, Wo, keyv, query, Wb, KVa, Qb);

    proj_qkv<<<dim3(8, 64, 3), 256, 0, stream>>>(Qb, KVa, Wb, bq, bk, bv, Qw, Kw, Vt);

    attn_kernel<<<dim3(16, 16, 4), 256, 0, stream>>>(Qw, Kw, Vt, Cw);

    gemm_o<<<dim3(8, 64), 256, 0, stream>>>(Cw, Wb + (3l << 20), bo, (float*)d_out);
}

// Round 2
// 336.764 us; speedup vs baseline: 2.2906x; 2.2906x over previous
//
#include <hip/hip_runtime.h>

typedef __bf16 bf16;
typedef __bf16 bf16x8 __attribute__((ext_vector_type(8)));
typedef __bf16 bf16x4 __attribute__((ext_vector_type(4)));
typedef _Float16 f16;
typedef _Float16 f16x2 __attribute__((ext_vector_type(2)));
typedef _Float16 f16x4 __attribute__((ext_vector_type(4)));
typedef _Float16 f16x8 __attribute__((ext_vector_type(8)));
typedef float f32x4 __attribute__((ext_vector_type(4)));

__device__ __forceinline__ f32x4 mfma_qk(bf16x8 a, bf16x8 b, f32x4 c) {
    return __builtin_amdgcn_mfma_f32_16x16x32_bf16(a, b, c, 0, 0, 0);
}
// full-rate K=32 f16 MFMA for PV (legacy 16x16x16 runs at half rate)
__device__ __forceinline__ f32x4 mfma_pv32(f16x8 a, f16x8 b, f32x4 c) {
    return __builtin_amdgcn_mfma_f32_16x16x32_f16(a, b, c, 0, 0, 0);
}

// async global -> LDS, 16 bytes per lane (dest = wave-uniform base + lane*16)
#define GLOAD_LDS16(gp, lp)                                                    \
    __builtin_amdgcn_global_load_lds(                                          \
        (const __attribute__((address_space(1))) unsigned int*)(gp),           \
        (__attribute__((address_space(3))) unsigned int*)(lp), 16, 0, 0)

// ---------------------------------------------------------------------------
// Cast fp32 -> bf16: 4 weights (1024^2 each), key_value (8M), query (8M).
// ---------------------------------------------------------------------------
__global__ __launch_bounds__(256) void cast_inputs(
    const float* __restrict__ w0, const float* __restrict__ w1,
    const float* __restrict__ w2, const float* __restrict__ w3,
    const float* __restrict__ kv, const float* __restrict__ q,
    bf16* __restrict__ Wb, bf16* __restrict__ KVa, bf16* __restrict__ Qb) {
    long i4 = (long)blockIdx.x * 256 + threadIdx.x;  // float4 index
    const float* src;
    bf16* dst;
    long loc;
    if (i4 < 1048576) {            // 4 weights x 262144 float4
        int which = (int)(i4 >> 18);
        loc = (i4 & 262143) << 2;
        src = which == 0 ? w0 : which == 1 ? w1 : which == 2 ? w2 : w3;
        dst = Wb + ((long)which << 20);
    } else if (i4 < 3145728) {     // key_value
        loc = (i4 - 1048576) << 2;
        src = kv; dst = KVa;
    } else {                       // query
        loc = (i4 - 3145728) << 2;
        src = q; dst = Qb;
    }
    float4 f = *(const float4*)(src + loc);
    bf16x4 o;
    o[0] = (bf16)f.x; o[1] = (bf16)f.y; o[2] = (bf16)f.z; o[3] = (bf16)f.w;
    *(bf16x4*)(dst + loc) = o;
}

// ---------------------------------------------------------------------------
// Core GEMM: C[M,N] = A[M,K] @ W[N,K]^T + bias. M=8192, N=K=1024.
// 128x128 tile, BK=64, 4 waves each 64x64. Async global->LDS staging into
// XOR-swizzled pad-free layout: slot(row, c8) = row*8 + (c8 ^ (row&7));
// fragment b128 reads then spread over 8 bank-groups (conflict-free).
// om: 0 = bf16 row-major, 1 = f32 row-major, 2 = f16 V^T [b,h,d,skv].
// ---------------------------------------------------------------------------
__device__ __forceinline__ void gemm_core(
    const bf16* __restrict__ A, const bf16* __restrict__ Wt,
    const float* __restrict__ bias, void* __restrict__ Yv,
    const int om, bf16* smem, const int n0, const int m0) {
    constexpr int Kd = 1024, Nd = 1024;
    constexpr int TP = 132;  // om2 transpose row stride
    bf16* As = smem;          // 8192 halves (128 x 64, swizzled)
    bf16* Bs = smem + 8192;
    const int tid = threadIdx.x;
    const int wid = tid >> 6, lane = tid & 63;
    const int l16 = lane & 15, quad = lane >> 4;
    const int mh = (wid >> 1) * 64, nh = (wid & 1) * 64;

    f32x4 acc[4][4];
#pragma unroll
    for (int i = 0; i < 4; ++i)
#pragma unroll
        for (int j = 0; j < 4; ++j) acc[i][j] = (f32x4){0.f, 0.f, 0.f, 0.f};

    for (int k0 = 0; k0 < Kd; k0 += 64) {
#pragma unroll
        for (int j = 0; j < 4; ++j) {
            const int s = j * 256 + tid;
            const int r = s >> 3, c8 = (s & 7) ^ (r & 7);
            GLOAD_LDS16(A + (long)(m0 + r) * Kd + k0 + c8 * 8, &As[s * 8]);
            GLOAD_LDS16(Wt + (long)(n0 + r) * Kd + k0 + c8 * 8, &Bs[s * 8]);
        }
        __syncthreads();
#pragma unroll
        for (int kc = 0; kc < 2; ++kc) {
            bf16x8 af[4], bq[4];
#pragma unroll
            for (int i = 0; i < 4; ++i) {
                const int row = mh + i * 16 + l16;
                af[i] = *(const bf16x8*)&As[(row * 8 + ((kc * 4 + quad) ^ (row & 7))) * 8];
            }
#pragma unroll
            for (int i = 0; i < 4; ++i) {
                const int row = nh + i * 16 + l16;
                bq[i] = *(const bf16x8*)&Bs[(row * 8 + ((kc * 4 + quad) ^ (row & 7))) * 8];
            }
#pragma unroll
            for (int i = 0; i < 4; ++i)
#pragma unroll
                for (int j = 0; j < 4; ++j)
                    acc[i][j] = mfma_qk(af[i], bq[j], acc[i][j]);
        }
        __syncthreads();
    }

    if (om == 2) {
        // transpose tile through LDS as f16, then coalesced 16B stores
#pragma unroll
        for (int j = 0; j < 4; ++j) {
            const int col = nh + j * 16 + l16;
            const float bv = bias[n0 + col];
#pragma unroll
            for (int i = 0; i < 4; ++i)
#pragma unroll
                for (int p = 0; p < 2; ++p) {
                    f16x2 pk2;
                    pk2[0] = (f16)(acc[i][j][p * 2 + 0] + bv);
                    pk2[1] = (f16)(acc[i][j][p * 2 + 1] + bv);
                    *(f16x2*)&smem[col * TP + mh + i * 16 + quad * 4 + p * 2] = pk2;
                }
        }
        __syncthreads();
        // Vt[((b*16+h)*64+d)*2048 + skv]
        const int b_ = m0 >> 11, skv0 = m0 & 2047;
        const int rowc = tid & 15;
#pragma unroll
        for (int c = 0; c < 8; ++c) {
            const int col = (tid >> 4) + c * 16;
            const int colg = n0 + col;
            bf16x8 v = *(const bf16x8*)&smem[col * TP + rowc * 8];
            const long base = ((long)((b_ * 16 + (colg >> 6)) * 64 + (colg & 63))) << 11;
            *(bf16x8*)((bf16*)Yv + base + skv0 + rowc * 8) = v;
        }
    } else {
#pragma unroll
        for (int j = 0; j < 4; ++j) {
            const int col = n0 + nh + j * 16 + l16;
            const float bv = bias[col];
#pragma unroll
            for (int i = 0; i < 4; ++i)
#pragma unroll
                for (int r = 0; r < 4; ++r) {
                    int row = m0 + mh + i * 16 + quad * 4 + r;
                    float v = acc[i][j][r] + bv;
                    if (om == 1)
                        ((float*)Yv)[(long)row * Nd + col] = v;
                    else
                        ((bf16*)Yv)[(long)row * Nd + col] = (bf16)v;
                }
        }
    }
}

// Fused Q/K/V projections: one 1536-block launch (4 blocks/CU for the whole
// phase; the three GEMMs' barrier stalls hide each other). Chunked bijective
// XCD swizzle: each XCD gets 192 consecutive (z,y,x)-linear ids -> A-panel and
// W reuse stays within one XCD's L2.
__global__ __launch_bounds__(256) void proj_qkv(
    const bf16* __restrict__ Qb, const bf16* __restrict__ KVa,
    const bf16* __restrict__ Wb,
    const float* __restrict__ bq, const float* __restrict__ bk,
    const float* __restrict__ bv,
    bf16* __restrict__ Qw, bf16* __restrict__ Kw, f16* __restrict__ Vt) {
    __shared__ __align__(16) bf16 smem[16896];
    const int lin = blockIdx.x + (blockIdx.y << 3) + (blockIdx.z << 9);  // 0..1535
    const int nid = (lin & 7) * 192 + (lin >> 3);
    const int z = nid >> 9, rem = nid & 511;
    const int n0 = (rem & 7) << 7, m0 = (rem >> 3) << 7;
    if (z == 0)
        gemm_core(Qb, Wb, bq, Qw, 0, smem, n0, m0);
    else if (z == 1)
        gemm_core(KVa, Wb + (1l << 20), bk, Kw, 0, smem, n0, m0);
    else
        gemm_core(KVa, Wb + (2l << 20), bv, Vt, 2, smem, n0, m0);
}

__global__ __launch_bounds__(256) void gemm_o(
    const bf16* __restrict__ Cw, const bf16* __restrict__ Wo,
    const float* __restrict__ bo, float* __restrict__ out) {
    __shared__ __align__(16) bf16 smem[16896];
    const int lin = blockIdx.x + (blockIdx.y << 3);  // 0..511
    const int nid = (lin & 7) * 64 + (lin >> 3);
    gemm_core(Cw, Wo, bo, out, 1, smem, (nid & 7) << 7, (nid >> 3) << 7);
}

// ---------------------------------------------------------------------------
// StableMax cross-attention, transposed-score formulation.
// PV uses full-rate 16x16x32 f16 MFMA: the k-permutation inside the
// 32-chunk is chosen as  k-slot 8q+4s+r  <->  kv 16s+4q+r, which makes the
// two 16-row QK outputs land exactly in each lane's B-fragment slots (no
// cross-lane shuffles); V^T is fetched as two f16x4 chunks per MFMA.
// XCD-swizzled block ids keep each (b,h)'s 512KB K/V panel in one L2.
// NOTE: plain __launch_bounds__(256) — adding ",4" min-occupancy clamped the
// allocator to 64 VGPRs and spilled the 30+ live accumulator regs to scratch
// (R1: 1.2GB HBM writes, 4x slowdown). Do not re-add.
// ---------------------------------------------------------------------------
__global__ __launch_bounds__(256) void attn_kernel(
    const bf16* __restrict__ Q, const bf16* __restrict__ K,
    const f16* __restrict__ Vt, bf16* __restrict__ C) {
    constexpr int E = 1024, S = 2048;
    __shared__ __align__(16) char smem_raw[32768];
    bf16* Ks = (bf16*)smem_raw;             // [128 kv][64 d], swizzled chunks
    f16* VTs = (f16*)(smem_raw + 16384);    // [64 d][128 kv], swizzled chunks

    const int tid = threadIdx.x;
    const int wid = tid >> 6, lane = tid & 63;
    const int l16 = lane & 15, quad = lane >> 4;
    // chunked bijective XCD swizzle: 1024 blocks, 128 per XCD = 8 (b,h)
    // panels = 4MB K+V, exactly one XCD L2.
    const int lin = blockIdx.x + (blockIdx.y << 4) + (blockIdx.z << 8);
    const int nid = (lin & 7) * 128 + (lin >> 3);
    const int qt = nid & 15, h = (nid >> 4) & 15, b = nid >> 8;

    const long q0 = (long)b * S + qt * 128;
    const bf16* Qg = Q + q0 * E + h * 64;
    const bf16* Kg = K + (long)b * S * E + h * 64;
    const f16* Vg = Vt + ((long)(b * 16 + h) << 17);  // [d][2048]

    // Q B-fragments: B[k=d=quad*8+j][n=q=l16]
    bf16x8 qf[2][2];
#pragma unroll
    for (int mt = 0; mt < 2; ++mt)
#pragma unroll
        for (int kc = 0; kc < 2; ++kc)
            qf[mt][kc] = *(const bf16x8*)(Qg + (long)(wid * 32 + mt * 16 + l16) * E + kc * 32 + quad * 8);

    f32x4 ctx[2][4];   // ctx^T: lane holds d=dt*16+quad*4+r, q=l16
    float den[2] = {0.f, 0.f};
#pragma unroll
    for (int mt = 0; mt < 2; ++mt)
#pragma unroll
        for (int dt = 0; dt < 4; ++dt) ctx[mt][dt] = (f32x4){0.f, 0.f, 0.f, 0.f};

    for (int kv0 = 0; kv0 < S; kv0 += 128) {
        // stage K [128 kv][64 d]: swizzle slot = r*8 + (c8 ^ (r&7))
#pragma unroll
        for (int j = 0; j < 4; ++j) {
            const int s = j * 256 + tid;
            const int r = s >> 3, c8 = (s & 7) ^ (r & 7);
            GLOAD_LDS16(Kg + (long)(kv0 + r) * E + c8 * 8, &Ks[s * 8]);
        }
        // stage V^T [64 d][128 kv]: slot = r*16 + (c16 ^ (r&15))
#pragma unroll
        for (int j = 0; j < 4; ++j) {
            const int s = j * 256 + tid;
            const int r = s >> 4, c16 = (s & 15) ^ (r & 15);
            GLOAD_LDS16(Vg + (long)r * S + kv0 + c16 * 8, &VTs[s * 8]);
        }
        __syncthreads();

#pragma unroll
        for (int kvp = 0; kvp < 4; ++kvp) {
            // QK^T for the two 16-kv slices of this 32-chunk
            f32x4 sacc[2][2];  // [s][mt]
#pragma unroll
            for (int s = 0; s < 2; ++s) {
                const int rk = kvp * 32 + s * 16 + l16, rb = rk & 7;
                bf16x8 kf0 = *(const bf16x8*)&Ks[(rk * 8 + (quad ^ rb)) * 8];
                bf16x8 kf1 = *(const bf16x8*)&Ks[(rk * 8 + ((quad + 4) ^ rb)) * 8];
                __builtin_amdgcn_s_setprio(1);
#pragma unroll
                for (int mt = 0; mt < 2; ++mt) {
                    f32x4 t = mfma_qk(kf0, qf[mt][0], (f32x4){0.f, 0.f, 0.f, 0.f});
                    sacc[s][mt] = mfma_qk(kf1, qf[mt][1], t);
                }
                __builtin_amdgcn_s_setprio(0);
            }
            // stablemax: u = 1 + |x|/8 ; s = x>=0 ? u : 1/u; pack P as f16x8
            // B-fragment slot j = s*4+r at lane quad holds kv=16s+4*quad+r.
            f16x8 pp[2];
#pragma unroll
            for (int mt = 0; mt < 2; ++mt) {
#pragma unroll
                for (int s = 0; s < 2; ++s) {
                    float sv[4];
#pragma unroll
                    for (int r = 0; r < 4; ++r) {
                        float x = sacc[s][mt][r];
                        float u = __builtin_fmaf(__builtin_fabsf(x), 0.125f, 1.0f);
                        sv[r] = (x >= 0.f) ? u : __builtin_amdgcn_rcpf(u);
                        pp[mt][s * 4 + r] = (f16)sv[r];
                    }
                    den[mt] += (sv[0] + sv[1]) + (sv[2] + sv[3]);
                }
            }
            // PV: ctx^T += V^T-frag x P^T-frag (16x16x32 f16, full rate)
            // A-lane quad needs kv in {4q..4q+3} u {16+4q..16+4q+3}:
            // chunks c16l and c16l+2, half ho.
            const int c16l = 4 * kvp + (quad >> 1), ho = (quad & 1) * 4;
#pragma unroll
            for (int dt = 0; dt < 4; ++dt) {
                const int rv = dt * 16 + l16;
                f16x4 vlo = *(const f16x4*)&VTs[(rv * 16 + (c16l ^ l16)) * 8 + ho];
                f16x4 vhi = *(const f16x4*)&VTs[(rv * 16 + ((c16l + 2) ^ l16)) * 8 + ho];
                f16x8 vf = __builtin_shufflevector(vlo, vhi, 0, 1, 2, 3, 4, 5, 6, 7);
                __builtin_amdgcn_s_setprio(1);
#pragma unroll
                for (int mt = 0; mt < 2; ++mt)
                    ctx[mt][dt] = mfma_pv32(vf, pp[mt], ctx[mt][dt]);
                __builtin_amdgcn_s_setprio(0);
            }
        }
        __syncthreads();
    }

    // den: reduce across the 4 quads of each q column
    float scl[2];
#pragma unroll
    for (int mt = 0; mt < 2; ++mt) {
        float d = den[mt];
        d += __shfl_xor(d, 16);
        d += __shfl_xor(d, 32);
        scl[mt] = __builtin_amdgcn_rcpf(d);
    }

    // epilogue: ctx^T -> LDS transpose (overlay, stride 68) -> coalesced store
    bf16* Os = (bf16*)smem_raw;
#pragma unroll
    for (int mt = 0; mt < 2; ++mt)
#pragma unroll
        for (int dt = 0; dt < 4; ++dt) {
            bf16x4 o;
#pragma unroll
            for (int r = 0; r < 4; ++r) o[r] = (bf16)(ctx[mt][dt][r] * scl[mt]);
            *(bf16x4*)&Os[(wid * 32 + mt * 16 + l16) * 68 + dt * 16 + quad * 4] = o;
        }
    __syncthreads();
    {
        const int r = tid >> 1, c = (tid & 1) * 32;
        bf16* cp = C + (q0 + r) * E + h * 64 + c;
#pragma unroll
        for (int j = 0; j < 4; ++j)
            *(bf16x8*)(cp + j * 8) = *(const bf16x8*)&Os[r * 68 + c + j * 8];
    }
}

// ---------------------------------------------------------------------------
extern "C" void kernel_launch(void* const* d_in, const int* in_sizes, int n_in,
                              void* d_out, int out_size, void* d_ws, size_t ws_size,
                              hipStream_t stream) {
    const float* query = (const float*)d_in[0];
    const float* keyv  = (const float*)d_in[1];
    const float* Wq = (const float*)d_in[2];
    const float* bq = (const float*)d_in[3];
    const float* Wk = (const float*)d_in[4];
    const float* bk = (const float*)d_in[5];
    const float* Wv = (const float*)d_in[6];
    const float* bv = (const float*)d_in[7];
    const float* Wo = (const float*)d_in[8];
    const float* bo = (const float*)d_in[9];

    char* ws = (char*)d_ws;
    bf16* Wb  = (bf16*)ws;                  // 8 MB: Wq,Wk,Wv,Wo bf16
    bf16* KVa = (bf16*)(ws + (8l << 20));   // 16 MB kv bf16 (later Cw)
    bf16* Qb  = (bf16*)(ws + (24l << 20));  // 16 MB query bf16
    bf16* Qw  = (bf16*)(ws + (40l << 20));  // 16 MB
    f16*  Vt  = (f16*)(ws + (56l << 20));   // 16 MB V^T f16 [b,h,d,skv]
    bf16* Kw  = (bf16*)d_out;               // d_out dead until gemm_o: use as Kw
    bf16* Cw  = KVa;                        // alias: KVa dead after proj_qkv

    cast_inputs<<<20480, 256, 0, stream>>>(Wq, Wk, Wv, Wo, keyv, query, Wb, KVa, Qb);

    proj_qkv<<<dim3(8, 64, 3), 256, 0, stream>>>(Qb, KVa, Wb, bq, bk, bv, Qw, Kw, Vt);

    attn_kernel<<<dim3(16, 16, 4), 256, 0, stream>>>(Qw, Kw, Vt, Cw);

    gemm_o<<<dim3(8, 64), 256, 0, stream>>>(Cw, Wb + (3l << 20), bo, (float*)d_out);
}

// Round 3
// 329.538 us; speedup vs baseline: 2.3408x; 1.0219x over previous
//
#include <hip/hip_runtime.h>

typedef __bf16 bf16;
typedef __bf16 bf16x8 __attribute__((ext_vector_type(8)));
typedef __bf16 bf16x4 __attribute__((ext_vector_type(4)));
typedef _Float16 f16;
typedef _Float16 f16x2 __attribute__((ext_vector_type(2)));
typedef _Float16 f16x4 __attribute__((ext_vector_type(4)));
typedef _Float16 f16x8 __attribute__((ext_vector_type(8)));
typedef float f32x4 __attribute__((ext_vector_type(4)));

__device__ __forceinline__ f32x4 mfma_qk(bf16x8 a, bf16x8 b, f32x4 c) {
    return __builtin_amdgcn_mfma_f32_16x16x32_bf16(a, b, c, 0, 0, 0);
}
// full-rate K=32 f16 MFMA for PV (legacy 16x16x16 runs at half rate)
__device__ __forceinline__ f32x4 mfma_pv32(f16x8 a, f16x8 b, f32x4 c) {
    return __builtin_amdgcn_mfma_f32_16x16x32_f16(a, b, c, 0, 0, 0);
}

// async global -> LDS, 16 bytes per lane (dest = wave-uniform base + lane*16)
#define GLOAD_LDS16(gp, lp)                                                    \
    __builtin_amdgcn_global_load_lds(                                          \
        (const __attribute__((address_space(1))) unsigned int*)(gp),           \
        (__attribute__((address_space(3))) unsigned int*)(lp), 16, 0, 0)

// ---------------------------------------------------------------------------
// Cast fp32 -> bf16: 4 weights (1024^2 each), key_value (8M), query (8M).
// ---------------------------------------------------------------------------
__global__ __launch_bounds__(256) void cast_inputs(
    const float* __restrict__ w0, const float* __restrict__ w1,
    const float* __restrict__ w2, const float* __restrict__ w3,
    const float* __restrict__ kv, const float* __restrict__ q,
    bf16* __restrict__ Wb, bf16* __restrict__ KVa, bf16* __restrict__ Qb) {
    long i4 = (long)blockIdx.x * 256 + threadIdx.x;  // float4 index
    const float* src;
    bf16* dst;
    long loc;
    if (i4 < 1048576) {            // 4 weights x 262144 float4
        int which = (int)(i4 >> 18);
        loc = (i4 & 262143) << 2;
        src = which == 0 ? w0 : which == 1 ? w1 : which == 2 ? w2 : w3;
        dst = Wb + ((long)which << 20);
    } else if (i4 < 3145728) {     // key_value
        loc = (i4 - 1048576) << 2;
        src = kv; dst = KVa;
    } else {                       // query
        loc = (i4 - 3145728) << 2;
        src = q; dst = Qb;
    }
    float4 f = *(const float4*)(src + loc);
    bf16x4 o;
    o[0] = (bf16)f.x; o[1] = (bf16)f.y; o[2] = (bf16)f.z; o[3] = (bf16)f.w;
    *(bf16x4*)(dst + loc) = o;
}

// ---------------------------------------------------------------------------
// Core GEMM: C[M,N] = A[M,K] @ W[N,K]^T + bias. M=8192, N=K=1024.
// 128x128 tile, BK=64, 4 waves each 64x64. Async global->LDS staging into
// XOR-swizzled pad-free layout: slot(row, c8) = row*8 + (c8 ^ (row&7)).
// om: 0 = bf16 row-major, 1 = f32 row-major,
// om: 2 = f16 V^T [b,h,d,skv] with kv PERMUTED per 32-block:
//         chunk g (g=0..3) holds kv = 32B + {4g..4g+3, 16+4g..16+4g+3}
//         so the attn PV A-fragment is a single contiguous f16x8.
// ---------------------------------------------------------------------------
__device__ __forceinline__ void gemm_core(
    const bf16* __restrict__ A, const bf16* __restrict__ Wt,
    const float* __restrict__ bias, void* __restrict__ Yv,
    const int om, bf16* smem, const int n0, const int m0) {
    constexpr int Kd = 1024, Nd = 1024;
    constexpr int TP = 132;  // om2 transpose row stride
    bf16* As = smem;          // 8192 halves (128 x 64, swizzled)
    bf16* Bs = smem + 8192;
    const int tid = threadIdx.x;
    const int wid = tid >> 6, lane = tid & 63;
    const int l16 = lane & 15, quad = lane >> 4;
    const int mh = (wid >> 1) * 64, nh = (wid & 1) * 64;

    f32x4 acc[4][4];
#pragma unroll
    for (int i = 0; i < 4; ++i)
#pragma unroll
        for (int j = 0; j < 4; ++j) acc[i][j] = (f32x4){0.f, 0.f, 0.f, 0.f};

    for (int k0 = 0; k0 < Kd; k0 += 64) {
#pragma unroll
        for (int j = 0; j < 4; ++j) {
            const int s = j * 256 + tid;
            const int r = s >> 3, c8 = (s & 7) ^ (r & 7);
            GLOAD_LDS16(A + (long)(m0 + r) * Kd + k0 + c8 * 8, &As[s * 8]);
            GLOAD_LDS16(Wt + (long)(n0 + r) * Kd + k0 + c8 * 8, &Bs[s * 8]);
        }
        __syncthreads();
#pragma unroll
        for (int kc = 0; kc < 2; ++kc) {
            bf16x8 af[4], bq[4];
#pragma unroll
            for (int i = 0; i < 4; ++i) {
                const int row = mh + i * 16 + l16;
                af[i] = *(const bf16x8*)&As[(row * 8 + ((kc * 4 + quad) ^ (row & 7))) * 8];
            }
#pragma unroll
            for (int i = 0; i < 4; ++i) {
                const int row = nh + i * 16 + l16;
                bq[i] = *(const bf16x8*)&Bs[(row * 8 + ((kc * 4 + quad) ^ (row & 7))) * 8];
            }
#pragma unroll
            for (int i = 0; i < 4; ++i)
#pragma unroll
                for (int j = 0; j < 4; ++j)
                    acc[i][j] = mfma_qk(af[i], bq[j], acc[i][j]);
        }
        __syncthreads();
    }

    if (om == 2) {
        // transpose tile through LDS as f16, then coalesced 16B stores with
        // the per-32-block kv-group permutation applied on the way out.
#pragma unroll
        for (int j = 0; j < 4; ++j) {
            const int col = nh + j * 16 + l16;
            const float bv = bias[n0 + col];
#pragma unroll
            for (int i = 0; i < 4; ++i)
#pragma unroll
                for (int p = 0; p < 2; ++p) {
                    f16x2 pk2;
                    pk2[0] = (f16)(acc[i][j][p * 2 + 0] + bv);
                    pk2[1] = (f16)(acc[i][j][p * 2 + 1] + bv);
                    *(f16x2*)&smem[col * TP + mh + i * 16 + quad * 4 + p * 2] = pk2;
                }
        }
        __syncthreads();
        // Vt[((b*16+h)*64+d)*2048 + skv], permuted within each 32-kv block
        const int b_ = m0 >> 11, skv0 = m0 & 2047;
        const int rowc = tid & 15;                    // chunk within 128-kv tile
        const int B32 = (rowc >> 2) * 32, g4 = (rowc & 3) * 4;
        const f16* sm = (const f16*)smem;
#pragma unroll
        for (int c = 0; c < 8; ++c) {
            const int col = (tid >> 4) + c * 16;
            const int colg = n0 + col;
            f16x4 lo = *(const f16x4*)&sm[col * TP + B32 + g4];
            f16x4 hi = *(const f16x4*)&sm[col * TP + B32 + 16 + g4];
            f16x8 v = __builtin_shufflevector(lo, hi, 0, 1, 2, 3, 4, 5, 6, 7);
            const long base = ((long)((b_ * 16 + (colg >> 6)) * 64 + (colg & 63))) << 11;
            *(f16x8*)((f16*)Yv + base + skv0 + rowc * 8) = v;
        }
    } else {
#pragma unroll
        for (int j = 0; j < 4; ++j) {
            const int col = n0 + nh + j * 16 + l16;
            const float bv = bias[col];
#pragma unroll
            for (int i = 0; i < 4; ++i)
#pragma unroll
                for (int r = 0; r < 4; ++r) {
                    int row = m0 + mh + i * 16 + quad * 4 + r;
                    float v = acc[i][j][r] + bv;
                    if (om == 1)
                        ((float*)Yv)[(long)row * Nd + col] = v;
                    else
                        ((bf16*)Yv)[(long)row * Nd + col] = (bf16)v;
                }
        }
    }
}

// Fused Q/K/V projections: one 1536-block launch (4 blocks/CU for the whole
// phase). Chunked bijective XCD swizzle keeps A-panel / W reuse in one L2.
__global__ __launch_bounds__(256) void proj_qkv(
    const bf16* __restrict__ Qb, const bf16* __restrict__ KVa,
    const bf16* __restrict__ Wb,
    const float* __restrict__ bq, const float* __restrict__ bk,
    const float* __restrict__ bv,
    bf16* __restrict__ Qw, bf16* __restrict__ Kw, f16* __restrict__ Vt) {
    __shared__ __align__(16) bf16 smem[16896];
    const int lin = blockIdx.x + (blockIdx.y << 3) + (blockIdx.z << 9);  // 0..1535
    const int nid = (lin & 7) * 192 + (lin >> 3);
    const int z = nid >> 9, rem = nid & 511;
    const int n0 = (rem & 7) << 7, m0 = (rem >> 3) << 7;
    if (z == 0)
        gemm_core(Qb, Wb, bq, Qw, 0, smem, n0, m0);
    else if (z == 1)
        gemm_core(KVa, Wb + (1l << 20), bk, Kw, 0, smem, n0, m0);
    else
        gemm_core(KVa, Wb + (2l << 20), bv, Vt, 2, smem, n0, m0);
}

__global__ __launch_bounds__(256) void gemm_o(
    const bf16* __restrict__ Cw, const bf16* __restrict__ Wo,
    const float* __restrict__ bo, float* __restrict__ out) {
    __shared__ __align__(16) bf16 smem[16896];
    const int lin = blockIdx.x + (blockIdx.y << 3);  // 0..511
    const int nid = (lin & 7) * 64 + (lin >> 3);
    gemm_core(Cw, Wo, bo, out, 1, smem, (nid & 7) << 7, (nid >> 3) << 7);
}

// ---------------------------------------------------------------------------
// StableMax cross-attention, transposed-score formulation.
// R3: KVBLK=64 double-buffered T3-lite pipeline (stage t+1 before compute t,
// raw s_barrier + counted vmcnt(4) so prefetch loads stay in flight across
// barriers — never vmcnt(0) in the main loop). den computed via ones-MFMA
// (every lane gets the full denominator: no VALU adds, no final shuffle).
// V^T global is pre-permuted so the PV A-fragment is ONE ds_read_b128.
// NOTE: plain __launch_bounds__(256) — adding ",4" min-occupancy clamped the
// allocator to 64 VGPRs and spilled to scratch (R1: 1.2GB HBM writes, 4x
// slowdown). Do not re-add.
// ---------------------------------------------------------------------------
__global__ __launch_bounds__(256) void attn_kernel(
    const bf16* __restrict__ Q, const bf16* __restrict__ K,
    const f16* __restrict__ Vt, bf16* __restrict__ C) {
    constexpr int E = 1024, S = 2048, KVB = 64;
    __shared__ __align__(16) char smem_raw[32768];
    bf16* Ks0 = (bf16*)smem_raw;              // [64 kv][64 d] swizzled, 8KB
    bf16* Ks1 = (bf16*)(smem_raw + 8192);
    f16* Vt0 = (f16*)(smem_raw + 16384);      // [64 d][64 kv] swizzled, 8KB
    f16* Vt1 = (f16*)(smem_raw + 24576);

    const int tid = threadIdx.x;
    const int wid = tid >> 6, lane = tid & 63;
    const int l16 = lane & 15, quad = lane >> 4;
    // chunked bijective XCD swizzle: 1024 blocks, 128 per XCD = 8 (b,h)
    // panels = 4MB K+V, exactly one XCD L2.
    const int lin = blockIdx.x + (blockIdx.y << 4) + (blockIdx.z << 8);
    const int nid = (lin & 7) * 128 + (lin >> 3);
    const int qt = nid & 15, h = (nid >> 4) & 15, b = nid >> 8;

    const long q0 = (long)b * S + qt * 128;
    const bf16* Qg = Q + q0 * E + h * 64;
    const bf16* Kg = K + (long)b * S * E + h * 64;
    const f16* Vg = Vt + ((long)(b * 16 + h) << 17);  // [64 d][2048 kv] permuted

    // Q B-fragments: B[k=d=quad*8+j][n=q=l16]
    bf16x8 qf[2][2];
#pragma unroll
    for (int mt = 0; mt < 2; ++mt)
#pragma unroll
        for (int kc = 0; kc < 2; ++kc)
            qf[mt][kc] = *(const bf16x8*)(Qg + (long)(wid * 32 + mt * 16 + l16) * E + kc * 32 + quad * 8);

    f16x8 ones8;
#pragma unroll
    for (int j = 0; j < 8; ++j) ones8[j] = (f16)1.0f;

    f32x4 ctx[2][4];   // ctx^T: lane holds d=dt*16+quad*4+r, q=l16
    f32x4 dacc[2];     // ones-MFMA denominator accumulator (rows identical)
#pragma unroll
    for (int mt = 0; mt < 2; ++mt) {
        dacc[mt] = (f32x4){0.f, 0.f, 0.f, 0.f};
#pragma unroll
        for (int dt = 0; dt < 4; ++dt) ctx[mt][dt] = (f32x4){0.f, 0.f, 0.f, 0.f};
    }

    // stage one 64-kv tile: K [64 kv][64 d], V^T [64 d][64 kv] (both 8
    // chunks/row, slot = r*8 + (c ^ (r&7)), inverse-swizzle on global src)
    auto stage = [&](int kv0, bf16* Kd, f16* Vd) {
#pragma unroll
        for (int j = 0; j < 2; ++j) {
            const int s = j * 256 + tid;
            const int r = s >> 3, c8 = (s & 7) ^ (r & 7);
            GLOAD_LDS16(Kg + (long)(kv0 + r) * E + c8 * 8, &Kd[s * 8]);
        }
#pragma unroll
        for (int j = 0; j < 2; ++j) {
            const int s = j * 256 + tid;
            const int r = s >> 3, c8 = (s & 7) ^ (r & 7);
            GLOAD_LDS16(Vg + (long)r * S + kv0 + c8 * 8, &Vd[s * 8]);
        }
    };

    auto compute = [&](const bf16* Kc, const f16* Vc) {
#pragma unroll
        for (int kvp = 0; kvp < 2; ++kvp) {
            // QK^T for the two 16-kv slices of this 32-chunk
            f32x4 sacc[2][2];  // [sh][mt]
#pragma unroll
            for (int sh = 0; sh < 2; ++sh) {
                const int rk = kvp * 32 + sh * 16 + l16, rb = rk & 7;
                bf16x8 kf0 = *(const bf16x8*)&Kc[(rk * 8 + (quad ^ rb)) * 8];
                bf16x8 kf1 = *(const bf16x8*)&Kc[(rk * 8 + ((quad + 4) ^ rb)) * 8];
                __builtin_amdgcn_s_setprio(1);
#pragma unroll
                for (int mt = 0; mt < 2; ++mt) {
                    f32x4 t = mfma_qk(kf0, qf[mt][0], (f32x4){0.f, 0.f, 0.f, 0.f});
                    sacc[sh][mt] = mfma_qk(kf1, qf[mt][1], t);
                }
                __builtin_amdgcn_s_setprio(0);
            }
            // stablemax: u = 1 + |x|/8 ; s = x>=0 ? u : 1/u; pack P as f16x8
            // B-fragment slot j = sh*4+r at lane quad holds kv=16sh+4*quad+r.
            f16x8 pp[2];
#pragma unroll
            for (int mt = 0; mt < 2; ++mt)
#pragma unroll
                for (int sh = 0; sh < 2; ++sh)
#pragma unroll
                    for (int r = 0; r < 4; ++r) {
                        float x = sacc[sh][mt][r];
                        float u = __builtin_fmaf(__builtin_fabsf(x), 0.125f, 1.0f);
                        float sv = (x >= 0.f) ? u : __builtin_amdgcn_rcpf(u);
                        pp[mt][sh * 4 + r] = (f16)sv;
                    }
            // denominator via ones-A MFMA: D[m][n] = sum_k P[k][n] for all m
            __builtin_amdgcn_s_setprio(1);
            dacc[0] = mfma_pv32(ones8, pp[0], dacc[0]);
            dacc[1] = mfma_pv32(ones8, pp[1], dacc[1]);
            __builtin_amdgcn_s_setprio(0);
            // PV: ctx^T += V^T-frag x P^T-frag; permuted layout makes the
            // A-fragment one contiguous f16x8 per (dt, kvp)
            const int cL = 4 * kvp + quad;
#pragma unroll
            for (int dt = 0; dt < 4; ++dt) {
                const int rv = dt * 16 + l16;
                f16x8 vf = *(const f16x8*)&Vc[(rv * 8 + (cL ^ (rv & 7))) * 8];
                __builtin_amdgcn_s_setprio(1);
#pragma unroll
                for (int mt = 0; mt < 2; ++mt)
                    ctx[mt][dt] = mfma_pv32(vf, pp[mt], ctx[mt][dt]);
                __builtin_amdgcn_s_setprio(0);
            }
        }
    };

    // T3-lite pipeline: prologue stage tile 0; each iter stages tile t+1 into
    // the other buffer, waits vmcnt(4) (tile t done, t+1 still in flight),
    // barriers, computes tile t, barriers (protect buffer overwrite next iter).
    stage(0, Ks0, Vt0);
#pragma unroll 1
    for (int t = 0; t < 31; ++t) {
        const int sel = t & 1;
        stage((t + 1) * KVB, sel ? Ks0 : Ks1, sel ? Vt0 : Vt1);
        asm volatile("s_waitcnt vmcnt(4)\ns_barrier" ::: "memory");
        compute(sel ? Ks1 : Ks0, sel ? Vt1 : Vt0);
        asm volatile("s_waitcnt lgkmcnt(0)\ns_barrier" ::: "memory");
    }
    asm volatile("s_waitcnt vmcnt(0)\ns_barrier" ::: "memory");
    compute(Ks1, Vt1);  // tile 31 -> buffer 1
    __syncthreads();    // all LDS reads done before epilogue overlay

    // normalization: every lane already holds the full denominator for its
    // q-column (all 4 rows of dacc identical)
    float scl[2];
#pragma unroll
    for (int mt = 0; mt < 2; ++mt) scl[mt] = __builtin_amdgcn_rcpf(dacc[mt][0]);

    // epilogue: ctx^T -> LDS transpose (overlay, stride 68) -> coalesced store
    bf16* Os = (bf16*)smem_raw;
#pragma unroll
    for (int mt = 0; mt < 2; ++mt)
#pragma unroll
        for (int dt = 0; dt < 4; ++dt) {
            bf16x4 o;
#pragma unroll
            for (int r = 0; r < 4; ++r) o[r] = (bf16)(ctx[mt][dt][r] * scl[mt]);
            *(bf16x4*)&Os[(wid * 32 + mt * 16 + l16) * 68 + dt * 16 + quad * 4] = o;
        }
    __syncthreads();
    {
        const int r = tid >> 1, c = (tid & 1) * 32;
        bf16* cp = C + (q0 + r) * E + h * 64 + c;
#pragma unroll
        for (int j = 0; j < 4; ++j)
            *(bf16x8*)(cp + j * 8) = *(const bf16x8*)&Os[r * 68 + c + j * 8];
    }
}

// ---------------------------------------------------------------------------
extern "C" void kernel_launch(void* const* d_in, const int* in_sizes, int n_in,
                              void* d_out, int out_size, void* d_ws, size_t ws_size,
                              hipStream_t stream) {
    const float* query = (const float*)d_in[0];
    const float* keyv  = (const float*)d_in[1];
    const float* Wq = (const float*)d_in[2];
    const float* bq = (const float*)d_in[3];
    const float* Wk = (const float*)d_in[4];
    const float* bk = (const float*)d_in[5];
    const float* Wv = (const float*)d_in[6];
    const float* bv = (const float*)d_in[7];
    const float* Wo = (const float*)d_in[8];
    const float* bo = (const float*)d_in[9];

    char* ws = (char*)d_ws;
    bf16* Wb  = (bf16*)ws;                  // 8 MB: Wq,Wk,Wv,Wo bf16
    bf16* KVa = (bf16*)(ws + (8l << 20));   // 16 MB kv bf16 (later Cw)
    bf16* Qb  = (bf16*)(ws + (24l << 20));  // 16 MB query bf16
    bf16* Qw  = (bf16*)(ws + (40l << 20));  // 16 MB
    f16*  Vt  = (f16*)(ws + (56l << 20));   // 16 MB V^T f16 [b,h,d,skv] permuted
    bf16* Kw  = (bf16*)d_out;               // d_out dead until gemm_o: use as Kw
    bf16* Cw  = KVa;                        // alias: KVa dead after proj_qkv

    cast_inputs<<<20480, 256, 0, stream>>>(Wq, Wk, Wv, Wo, keyv, query, Wb, KVa, Qb);

    proj_qkv<<<dim3(8, 64, 3), 256, 0, stream>>>(Qb, KVa, Wb, bq, bk, bv, Qw, Kw, Vt);

    attn_kernel<<<dim3(16, 16, 4), 256, 0, stream>>>(Qw, Kw, Vt, Cw);

    gemm_o<<<dim3(8, 64), 256, 0, stream>>>(Cw, Wb + (3l << 20), bo, (float*)d_out);
}

// Round 6
// 312.854 us; speedup vs baseline: 2.4657x; 1.0533x over previous
//
#include <hip/hip_runtime.h>

typedef __bf16 bf16;
typedef __bf16 bf16x8 __attribute__((ext_vector_type(8)));
typedef __bf16 bf16x4 __attribute__((ext_vector_type(4)));
typedef _Float16 f16;
typedef _Float16 f16x2 __attribute__((ext_vector_type(2)));
typedef _Float16 f16x4 __attribute__((ext_vector_type(4)));
typedef _Float16 f16x8 __attribute__((ext_vector_type(8)));
typedef __fp16 h16x2 __attribute__((ext_vector_type(2)));  // cvt_pkrtz return type
typedef float f32x4 __attribute__((ext_vector_type(4)));

__device__ __forceinline__ f32x4 mfma_qk(bf16x8 a, bf16x8 b, f32x4 c) {
    return __builtin_amdgcn_mfma_f32_16x16x32_bf16(a, b, c, 0, 0, 0);
}
// full-rate K=32 f16 MFMA for PV (legacy 16x16x16 runs at half rate)
__device__ __forceinline__ f32x4 mfma_pv32(f16x8 a, f16x8 b, f32x4 c) {
    return __builtin_amdgcn_mfma_f32_16x16x32_f16(a, b, c, 0, 0, 0);
}
// pack two f32 -> f16x2 via v_cvt_pkrtz (bit-identical retype of __fp16 result)
__device__ __forceinline__ f16x2 pkrtz(float a, float b) {
    h16x2 r = __builtin_amdgcn_cvt_pkrtz(a, b);
    return __builtin_bit_cast(f16x2, r);
}

// async global -> LDS, 16 bytes per lane (dest = wave-uniform base + lane*16)
#define GLOAD_LDS16(gp, lp)                                                    \
    __builtin_amdgcn_global_load_lds(                                          \
        (const __attribute__((address_space(1))) unsigned int*)(gp),           \
        (__attribute__((address_space(3))) unsigned int*)(lp), 16, 0, 0)

// ---------------------------------------------------------------------------
// Cast fp32 -> bf16: 4 weights (1024^2 each), key_value (8M), query (8M).
// Wq is pre-scaled by 1/sqrt(HD)=0.125 (EXACT in bf16: exponent shift) so the
// attn kernel's scores arrive already scaled.
// ---------------------------------------------------------------------------
__global__ __launch_bounds__(256) void cast_inputs(
    const float* __restrict__ w0, const float* __restrict__ w1,
    const float* __restrict__ w2, const float* __restrict__ w3,
    const float* __restrict__ kv, const float* __restrict__ q,
    bf16* __restrict__ Wb, bf16* __restrict__ KVa, bf16* __restrict__ Qb) {
    long i4 = (long)blockIdx.x * 256 + threadIdx.x;  // float4 index
    const float* src;
    bf16* dst;
    long loc;
    float sc = 1.0f;
    if (i4 < 1048576) {            // 4 weights x 262144 float4
        int which = (int)(i4 >> 18);
        loc = (i4 & 262143) << 2;
        src = which == 0 ? w0 : which == 1 ? w1 : which == 2 ? w2 : w3;
        dst = Wb + ((long)which << 20);
        if (which == 0) sc = 0.125f;
    } else if (i4 < 3145728) {     // key_value
        loc = (i4 - 1048576) << 2;
        src = kv; dst = KVa;
    } else {                       // query
        loc = (i4 - 3145728) << 2;
        src = q; dst = Qb;
    }
    float4 f = *(const float4*)(src + loc);
    bf16x4 o;
    o[0] = (bf16)(f.x * sc); o[1] = (bf16)(f.y * sc);
    o[2] = (bf16)(f.z * sc); o[3] = (bf16)(f.w * sc);
    *(bf16x4*)(dst + loc) = o;
}

// ---------------------------------------------------------------------------
// Core GEMM: C[M,N] = A[M,K] @ W[N,K]^T + bias*bsc. M=8192, N=K=1024.
// 128x128 tile, BK=64, 4 waves each 64x64. Async global->LDS staging into
// XOR-swizzled pad-free layout: slot(row, c8) = row*8 + (c8 ^ (row&7)).
// om: 0 = bf16 row-major, 1 = f32 row-major,
// om: 2 = f16 V^T [b,h,d,skv] with kv PERMUTED per 32-block:
//         chunk g (g=0..3) holds kv = 32B + {4g..4g+3, 16+4g..16+4g+3}
//         so the attn PV A-fragment is a single contiguous f16x8.
// ---------------------------------------------------------------------------
__device__ __forceinline__ void gemm_core(
    const bf16* __restrict__ A, const bf16* __restrict__ Wt,
    const float* __restrict__ bias, void* __restrict__ Yv,
    const int om, bf16* smem, const int n0, const int m0, const float bsc) {
    constexpr int Kd = 1024, Nd = 1024;
    constexpr int TP = 132;  // om2 transpose row stride
    bf16* As = smem;          // 8192 halves (128 x 64, swizzled)
    bf16* Bs = smem + 8192;
    const int tid = threadIdx.x;
    const int wid = tid >> 6, lane = tid & 63;
    const int l16 = lane & 15, quad = lane >> 4;
    const int mh = (wid >> 1) * 64, nh = (wid & 1) * 64;

    f32x4 acc[4][4];
#pragma unroll
    for (int i = 0; i < 4; ++i)
#pragma unroll
        for (int j = 0; j < 4; ++j) acc[i][j] = (f32x4){0.f, 0.f, 0.f, 0.f};

    for (int k0 = 0; k0 < Kd; k0 += 64) {
#pragma unroll
        for (int j = 0; j < 4; ++j) {
            const int s = j * 256 + tid;
            const int r = s >> 3, c8 = (s & 7) ^ (r & 7);
            GLOAD_LDS16(A + (long)(m0 + r) * Kd + k0 + c8 * 8, &As[s * 8]);
            GLOAD_LDS16(Wt + (long)(n0 + r) * Kd + k0 + c8 * 8, &Bs[s * 8]);
        }
        __syncthreads();
#pragma unroll
        for (int kc = 0; kc < 2; ++kc) {
            bf16x8 af[4], bq[4];
#pragma unroll
            for (int i = 0; i < 4; ++i) {
                const int row = mh + i * 16 + l16;
                af[i] = *(const bf16x8*)&As[(row * 8 + ((kc * 4 + quad) ^ (row & 7))) * 8];
            }
#pragma unroll
            for (int i = 0; i < 4; ++i) {
                const int row = nh + i * 16 + l16;
                bq[i] = *(const bf16x8*)&Bs[(row * 8 + ((kc * 4 + quad) ^ (row & 7))) * 8];
            }
#pragma unroll
            for (int i = 0; i < 4; ++i)
#pragma unroll
                for (int j = 0; j < 4; ++j)
                    acc[i][j] = mfma_qk(af[i], bq[j], acc[i][j]);
        }
        __syncthreads();
    }

    if (om == 2) {
        // transpose tile through LDS as f16, then coalesced 16B stores with
        // the per-32-block kv-group permutation applied on the way out.
#pragma unroll
        for (int j = 0; j < 4; ++j) {
            const int col = nh + j * 16 + l16;
            const float bv = bias[n0 + col] * bsc;
#pragma unroll
            for (int i = 0; i < 4; ++i)
#pragma unroll
                for (int p = 0; p < 2; ++p) {
                    f16x2 pk2;
                    pk2[0] = (f16)(acc[i][j][p * 2 + 0] + bv);
                    pk2[1] = (f16)(acc[i][j][p * 2 + 1] + bv);
                    *(f16x2*)&smem[col * TP + mh + i * 16 + quad * 4 + p * 2] = pk2;
                }
        }
        __syncthreads();
        // Vt[((b*16+h)*64+d)*2048 + skv], permuted within each 32-kv block
        const int b_ = m0 >> 11, skv0 = m0 & 2047;
        const int rowc = tid & 15;                    // chunk within 128-kv tile
        const int B32 = (rowc >> 2) * 32, g4 = (rowc & 3) * 4;
        const f16* sm = (const f16*)smem;
#pragma unroll
        for (int c = 0; c < 8; ++c) {
            const int col = (tid >> 4) + c * 16;
            const int colg = n0 + col;
            f16x4 lo = *(const f16x4*)&sm[col * TP + B32 + g4];
            f16x4 hi = *(const f16x4*)&sm[col * TP + B32 + 16 + g4];
            f16x8 v = __builtin_shufflevector(lo, hi, 0, 1, 2, 3, 4, 5, 6, 7);
            const long base = ((long)((b_ * 16 + (colg >> 6)) * 64 + (colg & 63))) << 11;
            *(f16x8*)((f16*)Yv + base + skv0 + rowc * 8) = v;
        }
    } else {
#pragma unroll
        for (int j = 0; j < 4; ++j) {
            const int col = n0 + nh + j * 16 + l16;
            const float bv = bias[col] * bsc;
#pragma unroll
            for (int i = 0; i < 4; ++i)
#pragma unroll
                for (int r = 0; r < 4; ++r) {
                    int row = m0 + mh + i * 16 + quad * 4 + r;
                    float v = acc[i][j][r] + bv;
                    if (om == 1)
                        ((float*)Yv)[(long)row * Nd + col] = v;
                    else
                        ((bf16*)Yv)[(long)row * Nd + col] = (bf16)v;
                }
        }
    }
}

// Fused Q/K/V projections: one 1536-block launch (4 blocks/CU for the whole
// phase). Chunked bijective XCD swizzle keeps A-panel / W reuse in one L2.
__global__ __launch_bounds__(256) void proj_qkv(
    const bf16* __restrict__ Qb, const bf16* __restrict__ KVa,
    const bf16* __restrict__ Wb,
    const float* __restrict__ bq, const float* __restrict__ bk,
    const float* __restrict__ bv,
    bf16* __restrict__ Qw, bf16* __restrict__ Kw, f16* __restrict__ Vt) {
    __shared__ __align__(16) bf16 smem[16896];
    const int lin = blockIdx.x + (blockIdx.y << 3) + (blockIdx.z << 9);  // 0..1535
    const int nid = (lin & 7) * 192 + (lin >> 3);
    const int z = nid >> 9, rem = nid & 511;
    const int n0 = (rem & 7) << 7, m0 = (rem >> 3) << 7;
    if (z == 0)
        gemm_core(Qb, Wb, bq, Qw, 0, smem, n0, m0, 0.125f);  // Wq pre-scaled
    else if (z == 1)
        gemm_core(KVa, Wb + (1l << 20), bk, Kw, 0, smem, n0, m0, 1.0f);
    else
        gemm_core(KVa, Wb + (2l << 20), bv, Vt, 2, smem, n0, m0, 1.0f);
}

__global__ __launch_bounds__(256) void gemm_o(
    const bf16* __restrict__ Cw, const bf16* __restrict__ Wo,
    const float* __restrict__ bo, float* __restrict__ out) {
    __shared__ __align__(16) bf16 smem[16896];
    const int lin = blockIdx.x + (blockIdx.y << 3);  // 0..511
    const int nid = (lin & 7) * 64 + (lin >> 3);
    gemm_core(Cw, Wo, bo, out, 1, smem, (nid & 7) << 7, (nid >> 3) << 7, 1.0f);
}

// ---------------------------------------------------------------------------
// StableMax cross-attention, transposed-score formulation.
// R6 = R4 kernel with the cvt_pkrtz return-type fix (__fp16 vec -> bit_cast);
// R4/R5 never ran: R5 exposed the compile error, R4's "container failure" was
// most plausibly the same failure via a different infra path.
// R4 theory (attn is VALU-instruction bound: R2/R3 showed dur invariant to
// MFMA-rate and staging changes, VALUBusy 62%, HBM 4%):
//  - KVB=32, triple-buffered depth-2 pipeline, vmcnt(2) counted waits,
//    24KB LDS. stage = exactly 2 global_load_lds per tile.
//  - Zero-VALU LDS addressing: XOR chunk index is lane-constant, so all
//    ds_reads are [precomputed base VGPR + compile-time offset].
//  - P pack via v_cvt_pkrtz pairs (no per-element cvt+insert).
//  - scores pre-scaled via Wq/8 (exact), so u = |x|+1 is one v_add.
// NOTE: plain __launch_bounds__(256) — adding ",4" min-occupancy clamped the
// allocator to 64 VGPRs and spilled to scratch (R1: 1.2GB HBM writes, 4x
// slowdown). Do not re-add.
// ---------------------------------------------------------------------------
#define PWAIT2 asm volatile("s_waitcnt vmcnt(2) lgkmcnt(0)\ns_barrier" ::: "memory")
#define PWAIT0 asm volatile("s_waitcnt vmcnt(0) lgkmcnt(0)\ns_barrier" ::: "memory")

__global__ __launch_bounds__(256) void attn_kernel(
    const bf16* __restrict__ Q, const bf16* __restrict__ K,
    const f16* __restrict__ Vt, bf16* __restrict__ C) {
    constexpr int E = 1024, S = 2048;
    __shared__ __align__(16) char smem_raw[24576];  // 3 bufs x (4KB K + 4KB V)

    const int tid = threadIdx.x;
    const int wid = tid >> 6, lane = tid & 63;
    const int l16 = lane & 15, quad = lane >> 4;
    const int l7 = l16 & 7, l3 = l16 & 3;
    // chunked bijective XCD swizzle: 1024 blocks, 128 per XCD = 8 (b,h)
    // panels = 4MB K+V, exactly one XCD L2.
    const int lin = blockIdx.x + (blockIdx.y << 4) + (blockIdx.z << 8);
    const int nid = (lin & 7) * 128 + (lin >> 3);
    const int qt = nid & 15, h = (nid >> 4) & 15, b = nid >> 8;

    const long q0 = (long)b * S + qt * 128;
    const bf16* Qg = Q + q0 * E + h * 64;
    const bf16* Kg = K + (long)b * S * E + h * 64;
    const f16* Vg = Vt + ((long)(b * 16 + h) << 17);  // [64 d][2048 kv] permuted

    // Q B-fragments: B[k=d=quad*8+j][n=q=l16]  (Q already scaled by 1/8)
    bf16x8 qf[2][2];
#pragma unroll
    for (int mt = 0; mt < 2; ++mt)
#pragma unroll
        for (int kc = 0; kc < 2; ++kc)
            qf[mt][kc] = *(const bf16x8*)(Qg + (long)(wid * 32 + mt * 16 + l16) * E + kc * 32 + quad * 8);
    // drain Q loads so pipeline vmcnt counts see only the GLOADs
    asm volatile("s_waitcnt vmcnt(0)" ::: "memory");

    // per-lane staging source pointers (advance by uniform offsets per tile)
    const bf16* Ksrc = Kg + (long)(tid >> 3) * E + (((tid & 7) ^ ((tid >> 3) & 7)) * 8);
    const f16* Vsrc = Vg + (long)(tid >> 2) * S + (((tid & 3) ^ ((tid >> 2) & 3)) * 8);

    // precomputed per-lane LDS byte offsets (buf i: K at i*8192, V at +4096)
    int ka0[3], ka1[3], va[3];
#pragma unroll
    for (int i = 0; i < 3; ++i) {
        ka0[i] = i * 8192 + l16 * 128 + ((quad ^ l7) << 4);
        ka1[i] = i * 8192 + l16 * 128 + (((quad + 4) ^ l7) << 4);
        va[i]  = i * 8192 + 4096 + l16 * 64 + ((quad ^ l3) << 4);
    }

    f16x8 ones8;
#pragma unroll
    for (int j = 0; j < 8; ++j) ones8[j] = (f16)1.0f;

    f32x4 ctx[2][4];   // ctx^T: lane holds d=dt*16+quad*4+r, q=l16
    f32x4 dacc[2];     // ones-MFMA denominator accumulator (rows identical)
#pragma unroll
    for (int mt = 0; mt < 2; ++mt) {
        dacc[mt] = (f32x4){0.f, 0.f, 0.f, 0.f};
#pragma unroll
        for (int dt = 0; dt < 4; ++dt) ctx[mt][dt] = (f32x4){0.f, 0.f, 0.f, 0.f};
    }

    auto stage = [&](int kv0, int bi) {
        GLOAD_LDS16(Ksrc + (long)kv0 * E, smem_raw + bi * 8192 + tid * 16);
        GLOAD_LDS16(Vsrc + kv0, smem_raw + bi * 8192 + 4096 + tid * 16);
    };

    auto compute = [&](int bi) {
        f32x4 sacc[2][2];  // [sh][mt]
#pragma unroll
        for (int sh = 0; sh < 2; ++sh) {
            bf16x8 kf0 = *(const bf16x8*)(smem_raw + ka0[bi] + sh * 2048);
            bf16x8 kf1 = *(const bf16x8*)(smem_raw + ka1[bi] + sh * 2048);
            __builtin_amdgcn_s_setprio(1);
#pragma unroll
            for (int mt = 0; mt < 2; ++mt) {
                f32x4 t = mfma_qk(kf0, qf[mt][0], (f32x4){0.f, 0.f, 0.f, 0.f});
                sacc[sh][mt] = mfma_qk(kf1, qf[mt][1], t);
            }
            __builtin_amdgcn_s_setprio(0);
        }
        // stablemax (x pre-scaled): u = 1+|x|; s = x>=0 ? u : 1/u
        // pack P pairwise with cvt_pkrtz; k-slot j = sh*4+r holds kv=16sh+4q+r
        f16x8 pp[2];
#pragma unroll
        for (int mt = 0; mt < 2; ++mt) {
            float sv[8];
#pragma unroll
            for (int sh = 0; sh < 2; ++sh)
#pragma unroll
                for (int r = 0; r < 4; ++r) {
                    float x = sacc[sh][mt][r];
                    float u = __builtin_fabsf(x) + 1.0f;
                    sv[sh * 4 + r] = (x >= 0.f) ? u : __builtin_amdgcn_rcpf(u);
                }
            f16x2 w0 = pkrtz(sv[0], sv[1]);
            f16x2 w1 = pkrtz(sv[2], sv[3]);
            f16x2 w2 = pkrtz(sv[4], sv[5]);
            f16x2 w3 = pkrtz(sv[6], sv[7]);
            f16x4 lo = __builtin_shufflevector(w0, w1, 0, 1, 2, 3);
            f16x4 hi = __builtin_shufflevector(w2, w3, 0, 1, 2, 3);
            pp[mt] = __builtin_shufflevector(lo, hi, 0, 1, 2, 3, 4, 5, 6, 7);
        }
        // denominator via ones-A MFMA: every lane gets full den for its q-col
        __builtin_amdgcn_s_setprio(1);
        dacc[0] = mfma_pv32(ones8, pp[0], dacc[0]);
        dacc[1] = mfma_pv32(ones8, pp[1], dacc[1]);
        __builtin_amdgcn_s_setprio(0);
        // PV: ctx^T += V^T-frag x P^T-frag; permuted V layout -> one b128 read
#pragma unroll
        for (int dt = 0; dt < 4; ++dt) {
            f16x8 vf = *(const f16x8*)(smem_raw + va[bi] + dt * 1024);
            __builtin_amdgcn_s_setprio(1);
#pragma unroll
            for (int mt = 0; mt < 2; ++mt)
                ctx[mt][dt] = mfma_pv32(vf, pp[mt], ctx[mt][dt]);
            __builtin_amdgcn_s_setprio(0);
        }
    };

    // depth-2 pipeline over 64 tiles of 32 kv: at each wait, tile t is done
    // and tile t+1 is in flight (vmcnt(2) = the 2 loads of tile t+1).
    stage(0, 0);
    stage(32, 1);
    int kv = 64;
#pragma unroll 1
    for (int it = 0; it < 20; ++it) {
        PWAIT2; stage(kv, 2); compute(0); kv += 32;
        PWAIT2; stage(kv, 0); compute(1); kv += 32;
        PWAIT2; stage(kv, 1); compute(2); kv += 32;
    }
    PWAIT2; stage(kv, 2); compute(0);        // t=60, stage tile 62
    PWAIT2; stage(kv + 32, 0); compute(1);   // t=61, stage tile 63
    PWAIT2; compute(2);                      // t=62
    PWAIT0; compute(0);                      // t=63
    __syncthreads();

    // normalization: all 4 rows of dacc identical = full denominator
    float scl[2];
#pragma unroll
    for (int mt = 0; mt < 2; ++mt) scl[mt] = __builtin_amdgcn_rcpf(dacc[mt][0]);

    // epilogue: ctx^T -> LDS transpose (overlay, stride 68) -> coalesced store
    bf16* Os = (bf16*)smem_raw;
#pragma unroll
    for (int mt = 0; mt < 2; ++mt)
#pragma unroll
        for (int dt = 0; dt < 4; ++dt) {
            bf16x4 o;
#pragma unroll
            for (int r = 0; r < 4; ++r) o[r] = (bf16)(ctx[mt][dt][r] * scl[mt]);
            *(bf16x4*)&Os[(wid * 32 + mt * 16 + l16) * 68 + dt * 16 + quad * 4] = o;
        }
    __syncthreads();
    {
        const int r = tid >> 1, c = (tid & 1) * 32;
        bf16* cp = C + (q0 + r) * E + h * 64 + c;
#pragma unroll
        for (int j = 0; j < 4; ++j)
            *(bf16x8*)(cp + j * 8) = *(const bf16x8*)&Os[r * 68 + c + j * 8];
    }
}

// ---------------------------------------------------------------------------
extern "C" void kernel_launch(void* const* d_in, const int* in_sizes, int n_in,
                              void* d_out, int out_size, void* d_ws, size_t ws_size,
                              hipStream_t stream) {
    const float* query = (const float*)d_in[0];
    const float* keyv  = (const float*)d_in[1];
    const float* Wq = (const float*)d_in[2];
    const float* bq = (const float*)d_in[3];
    const float* Wk = (const float*)d_in[4];
    const float* bk = (const float*)d_in[5];
    const float* Wv = (const float*)d_in[6];
    const float* bv = (const float*)d_in[7];
    const float* Wo = (const float*)d_in[8];
    const float* bo = (const float*)d_in[9];

    char* ws = (char*)d_ws;
    bf16* Wb  = (bf16*)ws;                  // 8 MB: Wq/8,Wk,Wv,Wo bf16
    bf16* KVa = (bf16*)(ws + (8l << 20));   // 16 MB kv bf16 (later Cw)
    bf16* Qb  = (bf16*)(ws + (24l << 20));  // 16 MB query bf16
    bf16* Qw  = (bf16*)(ws + (40l << 20));  // 16 MB (holds q/8)
    f16*  Vt  = (f16*)(ws + (56l << 20));   // 16 MB V^T f16 [b,h,d,skv] permuted
    bf16* Kw  = (bf16*)d_out;               // d_out dead until gemm_o: use as Kw
    bf16* Cw  = KVa;                        // alias: KVa dead after proj_qkv

    cast_inputs<<<20480, 256, 0, stream>>>(Wq, Wk, Wv, Wo, keyv, query, Wb, KVa, Qb);

    proj_qkv<<<dim3(8, 64, 3), 256, 0, stream>>>(Qb, KVa, Wb, bq, bk, bv, Qw, Kw, Vt);

    attn_kernel<<<dim3(16, 16, 4), 256, 0, stream>>>(Qw, Kw, Vt, Cw);

    gemm_o<<<dim3(8, 64), 256, 0, stream>>>(Cw, Wb + (3l << 20), bo, (float*)d_out);
}